// Round 5
// baseline (112.268 us; speedup 1.0000x reference)
//
#include <hip/hip_runtime.h>
#include <hip/hip_bf16.h>
#include <stdint.h>

#define BB 64
#define NN 196
#define D1c 512
#define D2c 2048
#define HHc 512
#define MM (BB*NN)   // 12544

typedef __attribute__((ext_vector_type(8))) short bf16x8;
typedef __attribute__((ext_vector_type(4))) float f32x4;

__device__ inline ushort f2bf(float f){
  uint32_t u = __float_as_uint(f);
  u += 0x7fff + ((u >> 16) & 1);   // RNE
  return (ushort)(u >> 16);
}
// hardware packed f32->bf16 (RNE), 1 instr per 2 floats
__device__ inline uint32_t cvtpk(float lo, float hi){
  uint32_t r;
  asm("v_cvt_pk_bf16_f32 %0, %1, %2" : "=v"(r) : "v"(lo), "v"(hi));
  return r;
}

// ---- W2 [2048][512] f32 -> w2t in MFMA-fragment order (bf16) ----
// frag addr(h,k) = (h>>4)*32768 + (k>>6)*1024 + ((k>>5)&1)*512
//                + ((k>>3)&3)*128 + (h&15)*8 + (k&7)
__global__ __launch_bounds__(256) void w2t_kernel(const float* __restrict__ W2,
                                                  ushort* __restrict__ w2t){
  __shared__ float tile[64][65];
  const int ktb = blockIdx.x;          // 32 tiles of 64 k
  const int ht  = blockIdx.y;          // 8 tiles of 64 h
  const int t = threadIdx.x;
  const int tr = t >> 4;               // 0..15
  const int tc = (t & 15) * 4;         // 0..60
  #pragma unroll
  for (int p = 0; p < 4; ++p){
    int k = p*16 + tr;
    float4 v = *(const float4*)(W2 + (size_t)(ktb*64 + k)*HHc + ht*64 + tc);
    tile[k][tc] = v.x; tile[k][tc+1] = v.y; tile[k][tc+2] = v.z; tile[k][tc+3] = v.w;
  }
  __syncthreads();
  #pragma unroll
  for (int pp = 0; pp < 4; ++pp){
    int hl = pp*16 + tr;               // local h
    ushort4 o;
    o.x = f2bf(tile[tc  ][hl]);
    o.y = f2bf(tile[tc+1][hl]);
    o.z = f2bf(tile[tc+2][hl]);
    o.w = f2bf(tile[tc+3][hl]);
    size_t addr = (size_t)(ht*4 + pp)*32768 + (size_t)ktb*1024
                + (size_t)((tc>>5)&1)*512 + (size_t)((tc>>3)&3)*128
                + (size_t)tr*8 + (tc & 4);
    *(ushort4*)(w2t + addr) = o;
  }
}

// ---- enc1 = input1 @ W1 + b1   [64][512] f32 ----
__global__ __launch_bounds__(128) void enc1_kernel(const float* __restrict__ in1,
                                                   const float* __restrict__ W1,
                                                   const float* __restrict__ b1,
                                                   float* __restrict__ enc1){
  __shared__ float s1[D1c];
  const int b = blockIdx.x;
  const int ht = blockIdx.y;
  const int t = threadIdx.x;
  ((float4*)s1)[t] = ((const float4*)(in1 + (size_t)b*D1c))[t];
  __syncthreads();
  const int h = ht*128 + t;
  float acc = b1[h];
  #pragma unroll 8
  for (int d = 0; d < D1c; ++d)
    acc += s1[d] * W1[(size_t)d*HHc + h];
  enc1[b*HHc + h] = acc;
}

// ---- fused scores GEMM:  scores[m] += sum_h relu(A@W2 + b2 + enc1) * Wf ----
// tile: 64m x 128h (h-split 4 -> 784 blocks), BK=64, 4 waves each 64m x 32h.
// A: LDS-staged (cvt_pk, XOR swizzle), dbuf; depth-2 reg prefetch.
// B: fragment-ordered w2t (L2-resident), reg double-buffer, no LDS.
__global__ __launch_bounds__(256,3) void score_gemm(
    const float*  __restrict__ in2,
    const ushort* __restrict__ w2t,     // fragment-ordered bf16
    const float*  __restrict__ b2,
    const float*  __restrict__ wf,
    const float*  __restrict__ enc1,    // [64][512]
    float*        __restrict__ scores)  // [12544], pre-zeroed
{
  __shared__ ushort As[2][64*64];    // [row][k], 16B-chunk XOR swizzle c^=(row&7)

  const int t = threadIdx.x;
  // bijective XCD swizzle: 784 blocks = 8 XCD x 98; 4 h-blocks of an m-panel adjacent
  const int p  = blockIdx.x;
  const int lg = (p & 7) * 98 + (p >> 3);
  const int h0 = (lg & 3) * 128;
  const int m0 = (lg >> 2) * 64;

  const int wave = t >> 6, lane = t & 63;
  const int l15 = lane & 15, l4 = lane >> 4;

  // A staging: thread -> row t>>2, k-quarter (t&3)*16 (4 consecutive float4)
  const int arow = t >> 2;
  const int aq   = t & 3;
  const float* aBase = in2 + (size_t)(m0 + arow)*D2c + aq*16;
  const int ac0 = ((aq*2    ) ^ (arow & 7)) << 3;
  const int ac1 = ((aq*2 + 1) ^ (arow & 7)) << 3;

  // B fragment base for this wave/lane (wave owns h0+wave*32 .. +32)
  const ushort* bBase = w2t + (size_t)h0*2048 + (size_t)wave*65536 + lane*8;

  float b2v[2], wfv[2];
  #pragma unroll
  for (int hf = 0; hf < 2; ++hf){
    int hc = h0 + wave*32 + hf*16 + l15;
    b2v[hf] = b2[hc]; wfv[hf] = wf[hc];
  }

  f32x4 acc[4][2];
  #pragma unroll
  for (int i = 0; i < 4; ++i)
    #pragma unroll
    for (int j = 0; j < 2; ++j) acc[i][j] = (f32x4)0.f;

  float4 aRegA[4], aRegB[4];
  bf16x8 bRegA[4], bRegB[4];

#define A_LOAD(kt, R)                                                        \
  { _Pragma("unroll")                                                        \
    for (int j = 0; j < 4; ++j)                                              \
      R[j] = *(const float4*)(aBase + (kt)*64 + j*4); }

#define B_LOAD(kt, Bv)                                                       \
  { _Pragma("unroll")                                                        \
    for (int f = 0; f < 4; ++f)                                              \
      Bv[f] = *(const bf16x8*)(bBase + (f>>1)*32768 + (kt)*1024 + (f&1)*512); }

#define A_WRITE(R, buf)                                                      \
  { uint4 w0, w1;                                                            \
    w0.x = cvtpk(R[0].x, R[0].y); w0.y = cvtpk(R[0].z, R[0].w);              \
    w0.z = cvtpk(R[1].x, R[1].y); w0.w = cvtpk(R[1].z, R[1].w);              \
    w1.x = cvtpk(R[2].x, R[2].y); w1.y = cvtpk(R[2].z, R[2].w);              \
    w1.z = cvtpk(R[3].x, R[3].y); w1.w = cvtpk(R[3].z, R[3].w);              \
    *(uint4*)(As[buf] + arow*64 + ac0) = w0;                                 \
    *(uint4*)(As[buf] + arow*64 + ac1) = w1; }

#define COMPUTE(buf, Bv)                                                     \
  { _Pragma("unroll")                                                        \
    for (int kk = 0; kk < 2; ++kk){                                          \
      bf16x8 af[4];                                                          \
      _Pragma("unroll")                                                      \
      for (int mf = 0; mf < 4; ++mf){                                        \
        int r = mf*16 + l15, c = kk*4 + l4;                                  \
        af[mf] = *(const bf16x8*)(As[buf] + r*64 + ((c ^ (r & 7)) << 3)); }  \
      _Pragma("unroll")                                                      \
      for (int mf = 0; mf < 4; ++mf)                                         \
        _Pragma("unroll")                                                    \
        for (int hf = 0; hf < 2; ++hf)                                       \
          acc[mf][hf] = __builtin_amdgcn_mfma_f32_16x16x32_bf16(             \
              af[mf], Bv[hf*2+kk], acc[mf][hf], 0, 0, 0); } }

#define LGKM0() asm volatile("s_waitcnt lgkmcnt(0)" ::: "memory")
#define SB0()   __builtin_amdgcn_sched_barrier(0)
#define BAR()   { SB0(); __builtin_amdgcn_s_barrier(); SB0(); }

  // prologue
  A_LOAD(0, aRegA);
  B_LOAD(0, bRegA);
  A_LOAD(1, aRegB);
  A_WRITE(aRegA, 0);         // compiler inserts vmcnt wait for aRegA
  LGKM0();
  BAR();

  #pragma unroll 1
  for (int kt = 0; kt < 30; kt += 2){
    // even: compute As[0]/bRegA; prefetch B(kt+1), A(kt+2); write A(kt+1)->As[1]
    B_LOAD(kt + 1, bRegB);
    A_LOAD(kt + 2, aRegA);
    COMPUTE(0, bRegA);
    A_WRITE(aRegB, 1);
    LGKM0();
    BAR();
    // odd: compute As[1]/bRegB; prefetch B(kt+2), A(kt+3); write A(kt+2)->As[0]
    B_LOAD(kt + 2, bRegA);
    A_LOAD(kt + 3, aRegB);
    COMPUTE(1, bRegB);
    A_WRITE(aRegA, 0);
    LGKM0();
    BAR();
  }
  // kt = 30
  B_LOAD(31, bRegB);
  COMPUTE(0, bRegA);
  A_WRITE(aRegB, 1);
  LGKM0();
  BAR();
  // kt = 31
  COMPUTE(1, bRegB);

  // epilogue: relu + Wf partial over this wave's 32 h, atomic into scores
  #pragma unroll
  for (int mf = 0; mf < 4; ++mf){
    #pragma unroll
    for (int r = 0; r < 4; ++r){
      int m = m0 + mf*16 + l4*4 + r;   // C/D: row=(lane>>4)*4+reg, col=lane&15
      int b = m / NN;
      const float* e1 = enc1 + (size_t)b*HHc + h0 + wave*32 + l15;
      float s = 0.f;
      #pragma unroll
      for (int hf = 0; hf < 2; ++hf){
        float v = acc[mf][hf][r] + b2v[hf] + e1[hf*16];
        s += fmaxf(v, 0.f) * wfv[hf];
      }
      s += __shfl_xor(s, 1); s += __shfl_xor(s, 2);
      s += __shfl_xor(s, 4); s += __shfl_xor(s, 8);
      if (l15 == 0) atomicAdd(&scores[m], s);
    }
  }
#undef A_LOAD
#undef B_LOAD
#undef A_WRITE
#undef COMPUTE
#undef LGKM0
#undef SB0
#undef BAR
}

// ---- softmax over N=196 per batch ----
__global__ __launch_bounds__(64) void softmax_kernel(const float* __restrict__ scores,
                                                     float* __restrict__ alpha){
  const int b = blockIdx.x, t = threadIdx.x;
  const float* s = scores + b*NN;
  float x[4]; float mx = -1e30f;
  #pragma unroll
  for (int i = 0; i < 4; ++i){
    int n = t + i*64;
    x[i] = (n < NN) ? s[n] : -1e30f;
    mx = fmaxf(mx, x[i]);
  }
  #pragma unroll
  for (int o = 1; o < 64; o <<= 1) mx = fmaxf(mx, __shfl_xor(mx, o));
  float sum = 0.f;
  #pragma unroll
  for (int i = 0; i < 4; ++i){
    int n = t + i*64;
    float e = (n < NN) ? __expf(x[i] - mx) : 0.f;
    x[i] = e; sum += e;
  }
  #pragma unroll
  for (int o = 1; o < 64; o <<= 1) sum += __shfl_xor(sum, o);
  float inv = 1.f / sum;
  #pragma unroll
  for (int i = 0; i < 4; ++i){
    int n = t + i*64;
    if (n < NN) alpha[b*NN + n] = x[i] * inv;
  }
}

// ---- att[b,d] = sum_n input2[b,n,d] * alpha[b,n] ----
__global__ __launch_bounds__(256) void att_kernel(const float* __restrict__ in2,
                                                  const float* __restrict__ alpha,
                                                  float* __restrict__ att){
  __shared__ float sal[NN];
  const int b = blockIdx.y;
  const int t = threadIdx.x;
  if (t < NN) sal[t] = alpha[b*NN + t];
  __syncthreads();
  const int d = blockIdx.x*256 + t;
  const float* src = in2 + (size_t)b*NN*D2c + d;
  float acc = 0.f;
  #pragma unroll 7
  for (int n = 0; n < NN; ++n)
    acc += src[(size_t)n*D2c] * sal[n];
  att[(size_t)b*D2c + d] = acc;
}

extern "C" void kernel_launch(void* const* d_in, const int* in_sizes, int n_in,
                              void* d_out, int out_size, void* d_ws, size_t ws_size,
                              hipStream_t stream){
  (void)in_sizes; (void)n_in; (void)out_size; (void)ws_size;
  const float* input1 = (const float*)d_in[0];
  const float* input2 = (const float*)d_in[1];
  const float* W1     = (const float*)d_in[2];
  const float* b1     = (const float*)d_in[3];
  const float* W2     = (const float*)d_in[4];
  const float* b2     = (const float*)d_in[5];
  const float* Wf     = (const float*)d_in[6];
  // d_in[7] = bf : softmax shift-invariant, provably unused.

  float* out   = (float*)d_out;
  float* att   = out;              // [64][2048]
  float* alpha = out + BB*D2c;     // [64][196]

  char*   ws     = (char*)d_ws;
  ushort* w2t    = (ushort*)ws;                              // 2 MiB (frag order)
  float*  enc1   = (float*)(ws + 2*1024*1024);               // 128 KiB
  float*  scores = (float*)(ws + 2*1024*1024 + 131072);      // 50 KiB

  hipMemsetAsync(scores, 0, MM*sizeof(float), stream);
  w2t_kernel<<<dim3(32, 8), 256, 0, stream>>>(W2, w2t);
  enc1_kernel<<<dim3(BB, 4), 128, 0, stream>>>(input1, W1, b1, enc1);
  score_gemm<<<dim3(784), 256, 0, stream>>>(input2, w2t, b2, Wf, enc1, scores);
  softmax_kernel<<<dim3(BB), 64, 0, stream>>>(scores, alpha);
  att_kernel<<<dim3(8, BB), 256, 0, stream>>>(input2, alpha, att);
}

// Round 6
// 104.273 us; speedup vs baseline: 1.0767x; 1.0767x over previous
//
#include <hip/hip_runtime.h>
#include <hip/hip_bf16.h>
#include <stdint.h>

#define BB 64
#define NN 196
#define D1c 512
#define D2c 2048
#define HHc 512
#define MM (BB*NN)   // 12544

typedef __attribute__((ext_vector_type(8))) short bf16x8;
typedef __attribute__((ext_vector_type(4))) float f32x4;

__device__ inline ushort f2bf(float f){
  uint32_t u = __float_as_uint(f);
  u += 0x7fff + ((u >> 16) & 1);   // RNE
  return (ushort)(u >> 16);
}
// hardware packed f32->bf16 (RNE), 1 instr per 2 floats
__device__ inline uint32_t cvtpk(float lo, float hi){
  uint32_t r;
  asm("v_cvt_pk_bf16_f32 %0, %1, %2" : "=v"(r) : "v"(lo), "v"(hi));
  return r;
}

// ---- W2 [2048][512] f32 -> w2t in MFMA-fragment order (bf16) ----
// frag addr(h,k) = (h>>4)*32768 + (k>>6)*1024 + ((k>>5)&1)*512
//                + ((k>>3)&3)*128 + (h&15)*8 + (k&7)
__global__ __launch_bounds__(256) void w2t_kernel(const float* __restrict__ W2,
                                                  ushort* __restrict__ w2t){
  __shared__ float tile[64][65];
  const int ktb = blockIdx.x;          // 32 tiles of 64 k
  const int ht  = blockIdx.y;          // 8 tiles of 64 h
  const int t = threadIdx.x;
  const int tr = t >> 4;               // 0..15
  const int tc = (t & 15) * 4;         // 0..60
  #pragma unroll
  for (int p = 0; p < 4; ++p){
    int k = p*16 + tr;
    float4 v = *(const float4*)(W2 + (size_t)(ktb*64 + k)*HHc + ht*64 + tc);
    tile[k][tc] = v.x; tile[k][tc+1] = v.y; tile[k][tc+2] = v.z; tile[k][tc+3] = v.w;
  }
  __syncthreads();
  #pragma unroll
  for (int pp = 0; pp < 4; ++pp){
    int hl = pp*16 + tr;               // local h
    ushort4 o;
    o.x = f2bf(tile[tc  ][hl]);
    o.y = f2bf(tile[tc+1][hl]);
    o.z = f2bf(tile[tc+2][hl]);
    o.w = f2bf(tile[tc+3][hl]);
    size_t addr = (size_t)(ht*4 + pp)*32768 + (size_t)ktb*1024
                + (size_t)((tc>>5)&1)*512 + (size_t)((tc>>3)&3)*128
                + (size_t)tr*8 + (tc & 4);
    *(ushort4*)(w2t + addr) = o;
  }
}

// ---- enc1 = input1 @ W1 + b1   [64][512] f32 ----
__global__ __launch_bounds__(128) void enc1_kernel(const float* __restrict__ in1,
                                                   const float* __restrict__ W1,
                                                   const float* __restrict__ b1,
                                                   float* __restrict__ enc1){
  __shared__ float s1[D1c];
  const int b = blockIdx.x;
  const int ht = blockIdx.y;
  const int t = threadIdx.x;
  ((float4*)s1)[t] = ((const float4*)(in1 + (size_t)b*D1c))[t];
  __syncthreads();
  const int h = ht*128 + t;
  float acc = b1[h];
  #pragma unroll 8
  for (int d = 0; d < D1c; ++d)
    acc += s1[d] * W1[(size_t)d*HHc + h];
  enc1[b*HHc + h] = acc;
}

// ---- fused scores GEMM:  scores[m] += sum_h relu(A@W2 + b2 + enc1) * Wf ----
// tile: 64m x 128h (h-split 4 -> 784 blocks), BK=64, 4 waves each 64m x 32h.
// A: COALESCED loads (16-lane groups read 256B contiguous per row), cvt_pk,
//    XOR-swizzled LDS, dbuf.  B: fragment-ordered w2t in regs (L2-resident).
__global__ __launch_bounds__(256,3) void score_gemm(
    const float*  __restrict__ in2,
    const ushort* __restrict__ w2t,     // fragment-ordered bf16
    const float*  __restrict__ b2,
    const float*  __restrict__ wf,
    const float*  __restrict__ enc1,    // [64][512]
    float*        __restrict__ scores)  // [12544], pre-zeroed
{
  __shared__ ushort As[2][64*64];    // [row][k], 16B-chunk XOR swizzle c^=(row&7)

  const int t = threadIdx.x;
  // bijective XCD swizzle: 784 blocks = 8 XCD x 98; 4 h-blocks of an m-panel adjacent
  const int p  = blockIdx.x;
  const int lg = (p & 7) * 98 + (p >> 3);
  const int h0 = (lg & 3) * 128;
  const int m0 = (lg >> 2) * 64;

  const int wave = t >> 6, lane = t & 63;
  const int l15 = lane & 15, l4 = lane >> 4;

  // A staging (coalesced): instr j -> row rA + j*4, 16 lanes cover 256B of a row
  const int rA = wave*16 + l4;         // base row, +j*4 per instr
  const float* aBase = in2 + (size_t)(m0 + rA)*D2c + l15*4;
  const int acw = l15 >> 1;            // 16B chunk index 0..7
  const int apar = (l15 & 1) * 4;      // halfword offset within chunk

  // B fragment base for this wave/lane (wave owns h0+wave*32 .. +32)
  const ushort* bBase = w2t + (size_t)h0*2048 + (size_t)wave*65536 + lane*8;

  float b2v[2], wfv[2];
  #pragma unroll
  for (int hf = 0; hf < 2; ++hf){
    int hc = h0 + wave*32 + hf*16 + l15;
    b2v[hf] = b2[hc]; wfv[hf] = wf[hc];
  }

  f32x4 acc[4][2];
  #pragma unroll
  for (int i = 0; i < 4; ++i)
    #pragma unroll
    for (int j = 0; j < 2; ++j) acc[i][j] = (f32x4)0.f;

  float4 aRegA[4], aRegB[4];
  bf16x8 bRegA[4], bRegB[4];

#define A_LOAD(kt, R)                                                        \
  { _Pragma("unroll")                                                        \
    for (int j = 0; j < 4; ++j)                                              \
      R[j] = *(const float4*)(aBase + (size_t)(j*4)*D2c + (kt)*64); }

#define B_LOAD(kt, Bv)                                                       \
  { _Pragma("unroll")                                                        \
    for (int f = 0; f < 4; ++f)                                              \
      Bv[f] = *(const bf16x8*)(bBase + (f>>1)*32768 + (kt)*1024 + (f&1)*512); }

#define A_WRITE(R, buf)                                                      \
  { _Pragma("unroll")                                                        \
    for (int j = 0; j < 4; ++j){                                             \
      int r = rA + j*4;                                                      \
      uint2 pk;                                                              \
      pk.x = cvtpk(R[j].x, R[j].y);                                          \
      pk.y = cvtpk(R[j].z, R[j].w);                                          \
      *(uint2*)(As[buf] + r*64 + ((acw ^ (r & 7)) << 3) + apar) = pk; } }

#define COMPUTE(buf, Bv)                                                     \
  { _Pragma("unroll")                                                        \
    for (int kk = 0; kk < 2; ++kk){                                          \
      bf16x8 af[4];                                                          \
      _Pragma("unroll")                                                      \
      for (int mf = 0; mf < 4; ++mf){                                        \
        int r = mf*16 + l15, c = kk*4 + l4;                                  \
        af[mf] = *(const bf16x8*)(As[buf] + r*64 + ((c ^ (r & 7)) << 3)); }  \
      _Pragma("unroll")                                                      \
      for (int mf = 0; mf < 4; ++mf)                                         \
        _Pragma("unroll")                                                    \
        for (int hf = 0; hf < 2; ++hf)                                       \
          acc[mf][hf] = __builtin_amdgcn_mfma_f32_16x16x32_bf16(             \
              af[mf], Bv[hf*2+kk], acc[mf][hf], 0, 0, 0); } }

#define LGKM0() asm volatile("s_waitcnt lgkmcnt(0)" ::: "memory")
#define SB0()   __builtin_amdgcn_sched_barrier(0)
#define BAR()   { SB0(); __builtin_amdgcn_s_barrier(); SB0(); }

  // prologue
  A_LOAD(0, aRegA);
  B_LOAD(0, bRegA);
  A_LOAD(1, aRegB);
  A_WRITE(aRegA, 0);         // compiler inserts vmcnt wait for aRegA
  LGKM0();
  BAR();

  #pragma unroll 1
  for (int kt = 0; kt < 30; kt += 2){
    // even: compute As[0]/bRegA; prefetch B(kt+1), A(kt+2); write A(kt+1)->As[1]
    B_LOAD(kt + 1, bRegB);
    A_LOAD(kt + 2, aRegA);
    COMPUTE(0, bRegA);
    A_WRITE(aRegB, 1);
    LGKM0();
    BAR();
    // odd: compute As[1]/bRegB; prefetch B(kt+2), A(kt+3); write A(kt+2)->As[0]
    B_LOAD(kt + 2, bRegA);
    A_LOAD(kt + 3, aRegB);
    COMPUTE(1, bRegB);
    A_WRITE(aRegA, 0);
    LGKM0();
    BAR();
  }
  // kt = 30
  B_LOAD(31, bRegB);
  COMPUTE(0, bRegA);
  A_WRITE(aRegB, 1);
  LGKM0();
  BAR();
  // kt = 31
  COMPUTE(1, bRegB);

  // epilogue: relu + Wf partial over this wave's 32 h, atomic into scores
  #pragma unroll
  for (int mf = 0; mf < 4; ++mf){
    #pragma unroll
    for (int r = 0; r < 4; ++r){
      int m = m0 + mf*16 + l4*4 + r;   // C/D: row=(lane>>4)*4+reg, col=lane&15
      int b = m / NN;
      const float* e1 = enc1 + (size_t)b*HHc + h0 + wave*32 + l15;
      float s = 0.f;
      #pragma unroll
      for (int hf = 0; hf < 2; ++hf){
        float v = acc[mf][hf][r] + b2v[hf] + e1[hf*16];
        s += fmaxf(v, 0.f) * wfv[hf];
      }
      s += __shfl_xor(s, 1); s += __shfl_xor(s, 2);
      s += __shfl_xor(s, 4); s += __shfl_xor(s, 8);
      if (l15 == 0) atomicAdd(&scores[m], s);
    }
  }
#undef A_LOAD
#undef B_LOAD
#undef A_WRITE
#undef COMPUTE
#undef LGKM0
#undef SB0
#undef BAR
}

// ---- softmax over N=196 per batch ----
__global__ __launch_bounds__(64) void softmax_kernel(const float* __restrict__ scores,
                                                     float* __restrict__ alpha){
  const int b = blockIdx.x, t = threadIdx.x;
  const float* s = scores + b*NN;
  float x[4]; float mx = -1e30f;
  #pragma unroll
  for (int i = 0; i < 4; ++i){
    int n = t + i*64;
    x[i] = (n < NN) ? s[n] : -1e30f;
    mx = fmaxf(mx, x[i]);
  }
  #pragma unroll
  for (int o = 1; o < 64; o <<= 1) mx = fmaxf(mx, __shfl_xor(mx, o));
  float sum = 0.f;
  #pragma unroll
  for (int i = 0; i < 4; ++i){
    int n = t + i*64;
    float e = (n < NN) ? __expf(x[i] - mx) : 0.f;
    x[i] = e; sum += e;
  }
  #pragma unroll
  for (int o = 1; o < 64; o <<= 1) sum += __shfl_xor(sum, o);
  float inv = 1.f / sum;
  #pragma unroll
  for (int i = 0; i < 4; ++i){
    int n = t + i*64;
    if (n < NN) alpha[b*NN + n] = x[i] * inv;
  }
}

// ---- att[b,d] = sum_n input2[b,n,d] * alpha[b,n] ----
__global__ __launch_bounds__(256) void att_kernel(const float* __restrict__ in2,
                                                  const float* __restrict__ alpha,
                                                  float* __restrict__ att){
  __shared__ float sal[NN];
  const int b = blockIdx.y;
  const int t = threadIdx.x;
  if (t < NN) sal[t] = alpha[b*NN + t];
  __syncthreads();
  const int d = blockIdx.x*256 + t;
  const float* src = in2 + (size_t)b*NN*D2c + d;
  float acc = 0.f;
  #pragma unroll 7
  for (int n = 0; n < NN; ++n)
    acc += src[(size_t)n*D2c] * sal[n];
  att[(size_t)b*D2c + d] = acc;
}

extern "C" void kernel_launch(void* const* d_in, const int* in_sizes, int n_in,
                              void* d_out, int out_size, void* d_ws, size_t ws_size,
                              hipStream_t stream){
  (void)in_sizes; (void)n_in; (void)out_size; (void)ws_size;
  const float* input1 = (const float*)d_in[0];
  const float* input2 = (const float*)d_in[1];
  const float* W1     = (const float*)d_in[2];
  const float* b1     = (const float*)d_in[3];
  const float* W2     = (const float*)d_in[4];
  const float* b2     = (const float*)d_in[5];
  const float* Wf     = (const float*)d_in[6];
  // d_in[7] = bf : softmax shift-invariant, provably unused.

  float* out   = (float*)d_out;
  float* att   = out;              // [64][2048]
  float* alpha = out + BB*D2c;     // [64][196]

  char*   ws     = (char*)d_ws;
  ushort* w2t    = (ushort*)ws;                              // 2 MiB (frag order)
  float*  enc1   = (float*)(ws + 2*1024*1024);               // 128 KiB
  float*  scores = (float*)(ws + 2*1024*1024 + 131072);      // 50 KiB

  hipMemsetAsync(scores, 0, MM*sizeof(float), stream);
  w2t_kernel<<<dim3(32, 8), 256, 0, stream>>>(W2, w2t);
  enc1_kernel<<<dim3(BB, 4), 128, 0, stream>>>(input1, W1, b1, enc1);
  score_gemm<<<dim3(784), 256, 0, stream>>>(input2, w2t, b2, Wf, enc1, scores);
  softmax_kernel<<<dim3(BB), 64, 0, stream>>>(scores, alpha);
  att_kernel<<<dim3(8, BB), 256, 0, stream>>>(input2, alpha, att);
}